// Round 1
// baseline (91.167 us; speedup 1.0000x reference)
//
#include <hip/hip_runtime.h>
#include <hip/hip_fp16.h>

#define OUT_UNITS 128
#define ROWS_PER_BLOCK 8   // 512 threads = 8 waves, one row per wave
#define NSTAGE 4           // per-wave LDS gather ring depth (1 KB/slot)

#define GLOBAL_AS __attribute__((address_space(1)))
#define LDS_AS    __attribute__((address_space(3)))

// ---------------- Kernel 0: fused prep -------------------------------------
// job A (i < n4):  w fp32 -> fp16 into workspace (float4 -> 4 halves)
// job B (i < nnz): CSR row pointers from sorted COO rows
__global__ void prep(const float4* __restrict__ w4, uint2* __restrict__ wh, int n4,
                     const int* __restrict__ rows, int* __restrict__ row_start,
                     int nnz, int n_rows) {
    int i = blockIdx.x * blockDim.x + threadIdx.x;
    if (i < n4) {
        float4 f = w4[i];
        __half2 h01 = __floats2half2_rn(f.x, f.y);
        __half2 h23 = __floats2half2_rn(f.z, f.w);
        wh[i] = make_uint2(*(unsigned*)&h01, *(unsigned*)&h23);
    }
    if (i < nnz) {
        int cur = rows[i];
        if (i == 0) {
            for (int r = 0; r <= cur; ++r) row_start[r] = 0;
        } else {
            int prev = rows[i - 1];
            for (int r = prev + 1; r <= cur; ++r) row_start[r] = i;
        }
        if (i == nnz - 1) {
            for (int r = cur + 1; r <= n_rows; ++r) row_start[r] = nnz;
        }
    }
}

// ---------------- Kernel 1: 8 waves/block, one row per wave ------------------
// Round 14 change: gather staging moved from VGPRs to a per-wave LDS ring via
// global_load_lds (dwordx4). Rationale: the old 2-stage register pipeline
// (qA/qB 32 + pA/pB 16 + acc 8 + addressing > 64 VGPRs) cannot fit the
// __launch_bounds__(512,8) cap of 64 VGPRs without scratch spills in the
// inner loop. LDS ring: 4 slots x 1 KB per wave; lane's 16B gathered chunk
// lands at slot_base + lane*16 (global_load_lds HW layout), which is exactly
// the quarter-wave layout (quarter q's w-row at +q*256, sub*16 within).
// Explicit s_waitcnt vmcnt(3) keeps 4 x 1KB gathers in flight per wave and
// never drains to 0 in the main loop. Inner-loop VGPRs ~30 -> no spills,
// true 32 waves/CU. LDS/block = 32 KB ring + 4 KB cv = 36 KB -> 4 blocks/CU
// (144/160 KB). Slot-reuse fence: consume's FMAs force lgkmcnt on the
// ds_read_b128 before sched_barrier(0), so the refill global_load_lds of the
// same slot cannot issue until the read retired.
__global__ __launch_bounds__(512, 8)
void spmm_row_wave(const float* __restrict__ vals,
                   const __half* __restrict__ wh,
                   const int* __restrict__ cols,
                   const int* __restrict__ row_start,
                   float* __restrict__ out,
                   int n_rows) {
    __shared__ int2 cvbuf[ROWS_PER_BLOCK][64];                       // 4 KB
    __shared__ __align__(16) char gbuf[ROWS_PER_BLOCK][NSTAGE][1024]; // 32 KB

    const int wave = __builtin_amdgcn_readfirstlane((int)(threadIdx.x >> 6));
    const int lane = threadIdx.x & 63;
    const int r    = blockIdx.x * ROWS_PER_BLOCK + wave;
    if (r >= n_rows) return;

    const int start   = row_start[r];
    const int end     = row_start[r + 1];
    const int quarter = lane >> 4;   // which nnz of the quad
    const int sub     = lane & 15;   // 16 lanes x 16B cover one 256B w row
    const char* __restrict__ whb = (const char*)wh;
    const int loff = sub << 4;       // sub*16 bytes
    int2* cv = cvbuf[wave];
    char* gb = &gbuf[wave][0][0];
    char* myq = gb + (lane << 4);    // this lane's 16B within a slot

    float4 accA = make_float4(0.f, 0.f, 0.f, 0.f);  // cols sub*8 + 0..3
    float4 accB = make_float4(0.f, 0.f, 0.f, 0.f);  // cols sub*8 + 4..7

#define ISSUE(j, slot)                                                         \
    do {                                                                       \
        int c_ = cv[4 * (j) + quarter].x;                                      \
        __builtin_amdgcn_global_load_lds(                                      \
            (const GLOBAL_AS void*)(whb + (((size_t)(unsigned)c_) << 8) + loff), \
            (LDS_AS void*)(gb + ((slot) << 10)), 16, 0, 0);                    \
    } while (0)

#define CONSUME(t, slot)                                                       \
    do {                                                                       \
        float v_ = __int_as_float(cv[4 * (t) + quarter].y);                    \
        uint4 q_ = *(const uint4*)(myq + ((slot) << 10));                      \
        const __half2* h_ = (const __half2*)&q_;                               \
        float2 f0 = __half22float2(h_[0]);                                     \
        float2 f1 = __half22float2(h_[1]);                                     \
        float2 f2 = __half22float2(h_[2]);                                     \
        float2 f3 = __half22float2(h_[3]);                                     \
        accA.x = fmaf(v_, f0.x, accA.x); accA.y = fmaf(v_, f0.y, accA.y);      \
        accA.z = fmaf(v_, f1.x, accA.z); accA.w = fmaf(v_, f1.y, accA.w);      \
        accB.x = fmaf(v_, f2.x, accB.x); accB.y = fmaf(v_, f2.y, accB.y);      \
        accB.z = fmaf(v_, f3.x, accB.z); accB.w = fmaf(v_, f3.y, accB.w);      \
    } while (0)

    for (int base = start; base < end; base += 64) {
        const int navail = min(64, end - base);
        // stage (c, v): pad lanes get (valid col, v=0)
        const int idx = base + min(lane, navail - 1);
        int   c_l = cols[idx];
        float v_l = (lane < navail) ? vals[idx] : 0.f;
        cv[lane] = make_int2(c_l, __float_as_int(v_l));
        // same-wave LDS: program-ordered, no barrier

        const int nquad  = (navail + 3) >> 2;
        const int nquad4 = (nquad + 3) & ~3;   // 4..16, multiple of 4

        // ---- prologue: fill the 4-slot ring (nquad4 >= 4 always) ----
#pragma unroll
        for (int j = 0; j < NSTAGE; ++j) ISSUE(j, j);

        // ---- main: consume oldest slot, refill it with quad t+4 ----
        int t = 0;
        for (; t + NSTAGE < nquad4; ++t) {
            const int slot = t & (NSTAGE - 1);
            asm volatile("s_waitcnt vmcnt(3)" ::: "memory");
            CONSUME(t, slot);
            __builtin_amdgcn_sched_barrier(0);  // ds_read retired before overwrite
            ISSUE(t + NSTAGE, slot);
        }

        // ---- drain: no more issues, consume remaining <=4 slots ----
        asm volatile("s_waitcnt vmcnt(0)" ::: "memory");
        for (; t < nquad4; ++t) {
            const int slot = t & (NSTAGE - 1);
            CONSUME(t, slot);
        }
    }

#undef ISSUE
#undef CONSUME

    // fold the 4 quarters (disjoint nnz subsets)
#pragma unroll
    for (int d = 16; d <= 32; d <<= 1) {
        accA.x += __shfl_xor(accA.x, d); accA.y += __shfl_xor(accA.y, d);
        accA.z += __shfl_xor(accA.z, d); accA.w += __shfl_xor(accA.w, d);
        accB.x += __shfl_xor(accB.x, d); accB.y += __shfl_xor(accB.y, d);
        accB.z += __shfl_xor(accB.z, d); accB.w += __shfl_xor(accB.w, d);
    }

    if (quarter == 0) {
        float4* o = (float4*)(out + (size_t)r * OUT_UNITS + sub * 8);
        o[0] = accA;
        o[1] = accB;
    }
}

extern "C" void kernel_launch(void* const* d_in, const int* in_sizes, int n_in,
                              void* d_out, int out_size, void* d_ws, size_t ws_size,
                              hipStream_t stream) {
    const float* vals = (const float*)d_in[0];
    const float* w    = (const float*)d_in[1];
    const int*   rows = (const int*)d_in[2];
    const int*   cols = (const int*)d_in[3];
    float* out = (float*)d_out;

    const int nnz    = in_sizes[0];
    const int n_rows = out_size / OUT_UNITS;  // 16384
    const int w_n    = in_sizes[1];           // 8192*128 = 1048576
    const int n4     = w_n / 4;

    // ws layout: [0, 64KB+4) row_start ; [128KB, 128KB+2MB) w fp16
    int*    row_start = (int*)d_ws;
    __half* wh        = (__half*)((char*)d_ws + (128 << 10));

    const int prep_threads = (nnz > n4) ? nnz : n4;
    prep<<<(prep_threads + 255) / 256, 256, 0, stream>>>(
        (const float4*)w, (uint2*)wh, n4, rows, row_start, nnz, n_rows);
    spmm_row_wave<<<(n_rows + ROWS_PER_BLOCK - 1) / ROWS_PER_BLOCK, 512, 0, stream>>>(
        vals, wh, cols, row_start, out, n_rows);
}